// Round 11
// baseline (181.197 us; speedup 1.0000x reference)
//
#include <hip/hip_runtime.h>
#include <hip/hip_cooperative_groups.h>

namespace cg = cooperative_groups;

#define NTOT 1024
#define CIN  256
#define BATCH 16
#define NH   8
#define KD   16
#define DV   32
#define L2E  1.44269504088896340736f

typedef unsigned short u16;
typedef unsigned int   u32;
typedef __attribute__((ext_vector_type(2)))  _Float16 f16x2;
typedef __attribute__((ext_vector_type(8)))  _Float16 f16x8;
typedef __attribute__((ext_vector_type(16))) float    f32x16;

__device__ inline f16x8 as_f16x8(uint4 u) { return __builtin_bit_cast(f16x8, u); }
__device__ inline f16x2 as_f16x2(u32 u)   { return __builtin_bit_cast(f16x2, u); }
__device__ inline u32 pkrtz(float a, float b) {
  return __builtin_bit_cast(u32, __builtin_amdgcn_cvt_pkrtz(a, b));
}
__device__ inline u16 f2h(float x) {
  return __builtin_bit_cast(u16, (_Float16)x);
}
__device__ inline float fexp2(float x) {
#if __has_builtin(__builtin_amdgcn_exp2f)
  return __builtin_amdgcn_exp2f(x);              // raw v_exp_f32
#else
  float r; asm("v_exp_f32 %0, %1" : "=v"(r) : "v"(x)); return r;
#endif
}
__device__ inline float dot2acc(u32 p2, float c) {
#if __has_builtin(__builtin_amdgcn_fdot2)
  const f16x2 one2 = __builtin_bit_cast(f16x2, (u32)0x3C003C00u);
  return __builtin_amdgcn_fdot2(as_f16x2(p2), one2, c, false);
#else
  const f16x2 v = as_f16x2(p2);
  return c + (float)v[0] + (float)v[1];
#endif
}

// ===========================================================================
// MEGA KERNEL (cooperative): 256 blocks x 1024 threads, 1 block/CU (96KB LDS),
// 4 phases with grid.sync() between them.  Saves 3 dispatch gaps.
// ===========================================================================
__global__ __launch_bounds__(1024) void mega(
    const float* __restrict__ X,
    const float* __restrict__ wq, const float* __restrict__ sq, const float* __restrict__ bq,
    const float* __restrict__ wk, const float* __restrict__ sk, const float* __restrict__ bk,
    const float* __restrict__ wv, const float* __restrict__ sv, const float* __restrict__ bv,
    const float* __restrict__ wp, const float* __restrict__ sp, const float* __restrict__ bp,
    u16* __restrict__ x_t,       // 8MB, reused as o_t in phases 2/3
    u16* __restrict__ q_t, u16* __restrict__ k_t, u16* __restrict__ v_h,
    u16* __restrict__ wqkv, u16* __restrict__ wph, float* __restrict__ ball,
    float* __restrict__ out)
{
  __shared__ __align__(16) char SMEM[98304];
  cg::grid_group grid = cg::this_grid();
  const int t    = threadIdx.x;
  const int bid  = blockIdx.x;
  const int lane = t & 63;
  const int w    = t >> 6;
  const int g = lane >> 5, nl = lane & 31;

  // ===================== phase 0: x transpose + weight prep =====================
  {
    const int q4 = t >> 8, tt = t & 255;       // quarter 0..3, 256 thr each
    const int ti = bid*4 + q4;                 // 1024 tiles
    const int n0 = (ti & 15)*64, c0 = ((ti >> 4) & 3)*64, b = ti >> 6;
    u16 (*T)[64] = (u16(*)[64])(SMEM + q4*8192);
    #pragma unroll
    for (int rr = 0; rr < 4; ++rr) {
      const int c  = rr*16 + (tt >> 4);
      const int n4 = (tt & 15)*4;
      const float4 v = *(const float4*)&X[((size_t)b*CIN + c0 + c)*NTOT + n0 + n4];
      ushort4 r; r.x = f2h(v.x); r.y = f2h(v.y); r.z = f2h(v.z); r.w = f2h(v.w);
      *(ushort4*)&T[c][n4] = r;
    }
    __syncthreads();
    const int nl2 = tt & 63;
    #pragma unroll
    for (int j = 0; j < 2; ++j) {
      const int oct = (tt >> 6)*2 + j;
      uint4 wv4;
      wv4.x = (u32)T[oct*8+0][nl2] | ((u32)T[oct*8+1][nl2] << 16);
      wv4.y = (u32)T[oct*8+2][nl2] | ((u32)T[oct*8+3][nl2] << 16);
      wv4.z = (u32)T[oct*8+4][nl2] | ((u32)T[oct*8+5][nl2] << 16);
      wv4.w = (u32)T[oct*8+6][nl2] | ((u32)T[oct*8+7][nl2] << 16);
      *(uint4*)&x_t[((size_t)b*NTOT + n0 + nl2)*CIN + c0 + oct*8] = wv4;
    }
    if (bid < 48) {                            // weights: 48 blocks x 16 rows
      const int row = bid*16 + (t >> 6);       // 0..767
      const int ln  = t & 63;
      const float* src; u16* dst; float sc, bi;
      if (row < 128)      { src = wq + (size_t)row*CIN;       sc = sq[row]*L2E;     bi = bq[row]*L2E;     dst = wqkv + (size_t)row*CIN; }
      else if (row < 256) { src = wk + (size_t)(row-128)*CIN; sc = sk[row-128];     bi = bk[row-128];     dst = wqkv + (size_t)row*CIN; }
      else if (row < 512) { src = wv + (size_t)(row-256)*CIN; sc = sv[row-256];     bi = bv[row-256];     dst = wqkv + (size_t)row*CIN; }
      else                { src = wp + (size_t)(row-512)*CIN; sc = sp[row-512];     bi = bp[row-512];     dst = wph + (size_t)(row-512)*CIN; }
      const float4 v = *(const float4*)&src[ln*4];
      ushort4 r;
      r.x = f2h(v.x*sc); r.y = f2h(v.y*sc); r.z = f2h(v.z*sc); r.w = f2h(v.w*sc);
      *(ushort4*)&dst[ln*4] = r;
      if (ln == 0) ball[row] = bi;
    }
  }
  grid.sync();

  // ===================== phase 1: QKV conv (BM=128, BN=256) =====================
  {
    u16* A_lds = (u16*)SMEM;            // 16 KB
    u16* B_lds = (u16*)(SMEM + 16384);  // 32 KB
    const int wm = w >> 3, wn = w & 7;  // 2 x 8 waves, wave tile 64m x 32n
    const int np = bid & 3, mp = (bid >> 2) & 3, b = bid >> 4;
    const int n0 = np*256, m0 = mp*128;
    f32x16 acc[2] = {};

    for (int c0 = 0; c0 < CIN; c0 += 64) {
      { const int row = t >> 3, ch = t & 7;
        *(uint4*)&A_lds[row*64 + ((ch ^ (row&7))*8)] =
            *(const uint4*)&wqkv[(size_t)(m0+row)*CIN + c0 + ch*8]; }
      #pragma unroll
      for (int r = 0; r < 2; ++r) {
        const int idx = t + r*1024, row = idx >> 3, ch = idx & 7;
        *(uint4*)&B_lds[row*64 + ((ch ^ (row&7))*8)] =
            *(const uint4*)&x_t[((size_t)b*NTOT + n0 + row)*CIN + c0 + ch*8];
      }
      __syncthreads();
      #pragma unroll
      for (int ks = 0; ks < 4; ++ks) {
        const int ch = 2*ks + g;
        const int ra0 = wm*64 + nl, ra1 = wm*64 + 32 + nl, rb = wn*32 + nl;
        const f16x8 a0 = as_f16x8(*(const uint4*)&A_lds[ra0*64 + ((ch ^ (ra0&7))*8)]);
        const f16x8 a1 = as_f16x8(*(const uint4*)&A_lds[ra1*64 + ((ch ^ (ra1&7))*8)]);
        const f16x8 bb = as_f16x8(*(const uint4*)&B_lds[rb*64 + ((ch ^ (rb&7))*8)]);
        acc[0] = __builtin_amdgcn_mfma_f32_32x32x16_f16(a0, bb, acc[0], 0, 0, 0);
        acc[1] = __builtin_amdgcn_mfma_f32_32x32x16_f16(a1, bb, acc[1], 0, 0, 0);
      }
      __syncthreads();
    }

    const int n = n0 + wn*32 + nl;
    #pragma unroll
    for (int fi = 0; fi < 2; ++fi) {
      #pragma unroll
      for (int q = 0; q < 4; ++q) {
        const int ob = m0 + wm*64 + fi*32 + 8*q + 4*g;   // wave-uniform
        const float v0 = acc[fi][4*q+0] + ball[ob+0];
        const float v1 = acc[fi][4*q+1] + ball[ob+1];
        const float v2 = acc[fi][4*q+2] + ball[ob+2];
        const float v3 = acc[fi][4*q+3] + ball[ob+3];
        if (ob < 128) {                       // Q rows
          const int h = ob >> 4, k0 = ob & 15;
          ushort4 r; r.x = f2h(v0); r.y = f2h(v1); r.z = f2h(v2); r.w = f2h(v3);
          *(ushort4*)&q_t[(((size_t)b*NH + h)*NTOT + n)*KD + k0] = r;
        } else if (ob < 256) {                // K rows -> plane layout
          const int oo = ob - 128;
          const int h = oo >> 4, k0 = oo & 15;
          const int plane = k0 >> 3, j0 = k0 & 7;
          ushort4 r; r.x = f2h(v0); r.y = f2h(v1); r.z = f2h(v2); r.w = f2h(v3);
          *(ushort4*)&k_t[((((size_t)b*NH + h)*2 + plane)*NTOT + n)*8 + j0] = r;
        } else {                              // V rows -> permuted layout
          const int oo = ob - 256;
          const int h = oo >> 5, d0 = oo & 31;
          const int mb = n >> 4, loc = n & 15;
          const int g2 = (loc >> 2) & 1;
          const int j  = (loc & 3) + ((loc >> 3) << 2);
          u16* vp = v_h + (((((size_t)b*NH + h)*64 + mb)*2 + g2)*32 + d0)*8 + j;
          vp[0*8] = f2h(v0);
          vp[1*8] = f2h(v1);
          vp[2*8] = f2h(v2);
          vp[3*8] = f2h(v3);
        }
      }
    }
  }
  grid.sync();

  // ===================== phase 2: attention (R10 body) =====================
  {
    u16* K_lds = (u16*)SMEM;            // 32 KB
    u16* V_lds = (u16*)(SMEM + 32768);  // 64 KB
    const int bh = bid >> 1, half = bid & 1;
    const int n0 = half*512 + w*32;

    const u16* Kh = k_t + (size_t)bh*(2*NTOT*8);
    const u16* Vh = v_h + (size_t)bh*(4096*8);
    const u16* Qh = q_t + (size_t)bh*(NTOT*KD);

    #pragma unroll
    for (int r = 0; r < 2; ++r) {
      const int uu = r*1024 + t;
      *(uint4*)&K_lds[uu*8] = *(const uint4*)&Kh[uu*8];
    }
    #pragma unroll
    for (int r = 0; r < 4; ++r) {
      const int uu = r*1024 + t;
      *(uint4*)&V_lds[uu*8] = *(const uint4*)&Vh[uu*8];
    }

    const f16x8 qf = as_f16x8(*(const uint4*)&Qh[(size_t)(n0+nl)*KD + g*8]);
    __syncthreads();

    const f32x16 fzero = {};
    f32x16 acc = {};
    float l0 = 0.f, l1 = 0.f, l2 = 0.f, l3 = 0.f;
    const char* Kb = (const char*)K_lds + g*16384 + nl*16;  // + step*512
    const char* Vb = (const char*)V_lds + g*512   + nl*16;  // + step*2048 (+1024)

    f16x8 kf  = as_f16x8(*(const uint4*)(Kb));
    uint4 va0 = *(const uint4*)(Vb);
    uint4 va1 = *(const uint4*)(Vb + 1024);
    f32x16 s_cur = __builtin_amdgcn_mfma_f32_32x32x16_f16(kf, qf, fzero, 0, 0, 0);

    #pragma unroll 2
    for (int st = 0; st < 31; ++st) {
      const f16x8 kfn = as_f16x8(*(const uint4*)(Kb + (st+1)*512));
      __builtin_amdgcn_s_setprio(1);
      const f32x16 s_next = __builtin_amdgcn_mfma_f32_32x32x16_f16(kfn, qf, fzero, 0, 0, 0);
      __builtin_amdgcn_s_setprio(0);
      const uint4 nva0 = *(const uint4*)(Vb + (st+1)*2048);
      const uint4 nva1 = *(const uint4*)(Vb + (st+1)*2048 + 1024);

      {
        float p[8];
        #pragma unroll
        for (int r = 0; r < 8; ++r) p[r] = fexp2(s_cur[r]);
        uint4 pb0;
        pb0.x = pkrtz(p[0], p[1]); pb0.y = pkrtz(p[2], p[3]);
        pb0.z = pkrtz(p[4], p[5]); pb0.w = pkrtz(p[6], p[7]);
        l0 = dot2acc(pb0.x, l0); l1 = dot2acc(pb0.y, l1);
        l2 = dot2acc(pb0.z, l2); l3 = dot2acc(pb0.w, l3);
        __builtin_amdgcn_s_setprio(1);
        acc = __builtin_amdgcn_mfma_f32_32x32x16_f16(as_f16x8(va0), as_f16x8(pb0), acc, 0, 0, 0);
        __builtin_amdgcn_s_setprio(0);
      }
      {
        float p[8];
        #pragma unroll
        for (int r = 0; r < 8; ++r) p[r] = fexp2(s_cur[8+r]);
        uint4 pb1;
        pb1.x = pkrtz(p[0], p[1]); pb1.y = pkrtz(p[2], p[3]);
        pb1.z = pkrtz(p[4], p[5]); pb1.w = pkrtz(p[6], p[7]);
        l0 = dot2acc(pb1.x, l0); l1 = dot2acc(pb1.y, l1);
        l2 = dot2acc(pb1.z, l2); l3 = dot2acc(pb1.w, l3);
        __builtin_amdgcn_s_setprio(1);
        acc = __builtin_amdgcn_mfma_f32_32x32x16_f16(as_f16x8(va1), as_f16x8(pb1), acc, 0, 0, 0);
        __builtin_amdgcn_s_setprio(0);
      }
      s_cur = s_next; va0 = nva0; va1 = nva1;
    }
    { // last step
      {
        float p[8];
        #pragma unroll
        for (int r = 0; r < 8; ++r) p[r] = fexp2(s_cur[r]);
        uint4 pb0;
        pb0.x = pkrtz(p[0], p[1]); pb0.y = pkrtz(p[2], p[3]);
        pb0.z = pkrtz(p[4], p[5]); pb0.w = pkrtz(p[6], p[7]);
        l0 = dot2acc(pb0.x, l0); l1 = dot2acc(pb0.y, l1);
        l2 = dot2acc(pb0.z, l2); l3 = dot2acc(pb0.w, l3);
        acc = __builtin_amdgcn_mfma_f32_32x32x16_f16(as_f16x8(va0), as_f16x8(pb0), acc, 0, 0, 0);
      }
      {
        float p[8];
        #pragma unroll
        for (int r = 0; r < 8; ++r) p[r] = fexp2(s_cur[8+r]);
        uint4 pb1;
        pb1.x = pkrtz(p[0], p[1]); pb1.y = pkrtz(p[2], p[3]);
        pb1.z = pkrtz(p[4], p[5]); pb1.w = pkrtz(p[6], p[7]);
        l0 = dot2acc(pb1.x, l0); l1 = dot2acc(pb1.y, l1);
        l2 = dot2acc(pb1.z, l2); l3 = dot2acc(pb1.w, l3);
        acc = __builtin_amdgcn_mfma_f32_32x32x16_f16(as_f16x8(va1), as_f16x8(pb1), acc, 0, 0, 0);
      }
    }

    const float lp = (l0 + l1) + (l2 + l3);
    const float lt = lp + __shfl_xor(lp, 32);
    const float rl = 1.0f / lt;
    const int b = bh >> 3, h = bh & 7;
    u16* op = x_t /*o_t*/ + ((size_t)b*NTOT + n0 + nl)*CIN + h*DV;
    #pragma unroll
    for (int q = 0; q < 4; ++q) {
      const float v0 = fmaxf(acc[4*q+0]*rl, 0.f);
      const float v1 = fmaxf(acc[4*q+1]*rl, 0.f);
      const float v2 = fmaxf(acc[4*q+2]*rl, 0.f);
      const float v3 = fmaxf(acc[4*q+3]*rl, 0.f);
      uint2 pk; pk.x = pkrtz(v0, v1); pk.y = pkrtz(v2, v3);
      *(uint2*)&op[8*q + 4*g] = pk;   // c = h*32 + 8q + 4g + {0..3}
    }
  }
  grid.sync();

  // ===================== phase 3: out-proj conv (BM=128, BN=128) =====================
  {
    u16* A_lds = (u16*)SMEM;            // 16 KB
    u16* B_lds = (u16*)(SMEM + 16384);  // 16 KB
    const int wm = w >> 2, wn = w & 3;  // 4 x 4 waves, wave tile 32m x 32n
    const int np = bid & 7, mp = (bid >> 3) & 1, b = bid >> 4;
    const int n0 = np*128, m0 = mp*128;
    const float* ball2 = ball + 512;
    f32x16 acc = {};

    for (int c0 = 0; c0 < CIN; c0 += 64) {
      { const int row = t >> 3, ch = t & 7;
        *(uint4*)&A_lds[row*64 + ((ch ^ (row&7))*8)] =
            *(const uint4*)&wph[(size_t)(m0+row)*CIN + c0 + ch*8]; }
      { const int row = t >> 3, ch = t & 7;
        *(uint4*)&B_lds[row*64 + ((ch ^ (row&7))*8)] =
            *(const uint4*)&x_t[((size_t)b*NTOT + n0 + row)*CIN + c0 + ch*8]; }
      __syncthreads();
      #pragma unroll
      for (int ks = 0; ks < 4; ++ks) {
        const int ch = 2*ks + g;
        const int ra = wm*32 + nl, rb = wn*32 + nl;
        const f16x8 a  = as_f16x8(*(const uint4*)&A_lds[ra*64 + ((ch ^ (ra&7))*8)]);
        const f16x8 bb = as_f16x8(*(const uint4*)&B_lds[rb*64 + ((ch ^ (rb&7))*8)]);
        acc = __builtin_amdgcn_mfma_f32_32x32x16_f16(a, bb, acc, 0, 0, 0);
      }
      __syncthreads();
    }

    const int n = n0 + wn*32 + nl;
    #pragma unroll
    for (int q = 0; q < 4; ++q) {
      const int ob = m0 + wm*32 + 8*q + 4*g;
      float* op = out + ((size_t)b*CIN + ob)*NTOT + n;
      op[0*NTOT] = acc[4*q+0] + ball2[ob+0];
      op[1*NTOT] = acc[4*q+1] + ball2[ob+1];
      op[2*NTOT] = acc[4*q+2] + ball2[ob+2];
      op[3*NTOT] = acc[4*q+3] + ball2[ob+3];
    }
  }
}

// ===========================================================================
// FALLBACK PATH (R10 kernels) — used only if cooperative launch fails.
// ===========================================================================
__global__ __launch_bounds__(256) void prep_fused(
    const float* __restrict__ X, u16* __restrict__ Xt,
    const float* __restrict__ wq, const float* __restrict__ sq, const float* __restrict__ bq,
    const float* __restrict__ wk, const float* __restrict__ sk, const float* __restrict__ bk,
    const float* __restrict__ wv, const float* __restrict__ sv, const float* __restrict__ bv,
    const float* __restrict__ wp, const float* __restrict__ sp, const float* __restrict__ bp,
    u16* __restrict__ wqkv, u16* __restrict__ wph, float* __restrict__ ball)
{
  __shared__ u16 T[64][64];
  const int bx = blockIdx.x;
  const int t  = threadIdx.x;
  if (bx < 1024) {
    const int n0 = (bx & 15) * 64;
    const int c0 = ((bx >> 4) & 3) * 64;
    const int b  = bx >> 6;
    #pragma unroll
    for (int rr = 0; rr < 4; ++rr) {
      const int c  = rr*16 + (t>>4);
      const int n4 = (t&15)*4;
      const float4 v = *(const float4*)&X[((size_t)b*CIN + c0 + c)*NTOT + n0 + n4];
      ushort4 r; r.x=f2h(v.x); r.y=f2h(v.y); r.z=f2h(v.z); r.w=f2h(v.w);
      *(ushort4*)&T[c][n4] = r;
    }
    __syncthreads();
    const int nl = t & 63;
    #pragma unroll
    for (int j = 0; j < 2; ++j) {
      const int oct = (t>>6)*2 + j;
      uint4 wv4;
      wv4.x = (u32)T[oct*8+0][nl] | ((u32)T[oct*8+1][nl] << 16);
      wv4.y = (u32)T[oct*8+2][nl] | ((u32)T[oct*8+3][nl] << 16);
      wv4.z = (u32)T[oct*8+4][nl] | ((u32)T[oct*8+5][nl] << 16);
      wv4.w = (u32)T[oct*8+6][nl] | ((u32)T[oct*8+7][nl] << 16);
      *(uint4*)&Xt[((size_t)b*NTOT + n0 + nl)*CIN + c0 + oct*8] = wv4;
    }
  } else {
    const int row = (bx - 1024)*4 + (t>>6);
    const int ln  = t & 63;
    const float* src; u16* dst; float sc, bi;
    if (row < 128)      { src = wq + (size_t)row*CIN;       sc = sq[row]*L2E;     bi = bq[row]*L2E;     dst = wqkv + (size_t)row*CIN; }
    else if (row < 256) { src = wk + (size_t)(row-128)*CIN; sc = sk[row-128];     bi = bk[row-128];     dst = wqkv + (size_t)row*CIN; }
    else if (row < 512) { src = wv + (size_t)(row-256)*CIN; sc = sv[row-256];     bi = bv[row-256];     dst = wqkv + (size_t)row*CIN; }
    else                { src = wp + (size_t)(row-512)*CIN; sc = sp[row-512];     bi = bp[row-512];     dst = wph + (size_t)(row-512)*CIN; }
    const float4 v = *(const float4*)&src[ln*4];
    ushort4 r;
    r.x = f2h(v.x*sc); r.y = f2h(v.y*sc); r.z = f2h(v.z*sc); r.w = f2h(v.w*sc);
    *(ushort4*)&dst[ln*4] = r;
    if (ln == 0) ball[row] = bi;
  }
}

template<int BN, int MODE>
__global__ __launch_bounds__(256) void conv_mfma(
    const u16* __restrict__ Wh, const u16* __restrict__ Bt,
    const float* __restrict__ ball,
    u16* __restrict__ q_t, u16* __restrict__ k_t, u16* __restrict__ v_h,
    float* __restrict__ outp)
{
  constexpr int FN = BN / 64;
  constexpr int NB = BN / 32;
  __shared__ u16 A_lds[2][128 * 64];
  __shared__ u16 B_lds[2][BN * 64];
  const int t    = threadIdx.x;
  const int lane = t & 63;
  const int w    = t >> 6;
  const int wm = w >> 1, wn = w & 1;
  const int g = lane >> 5, nl = lane & 31;
  const int n0 = blockIdx.x * BN;
  const int m0 = blockIdx.y * 128;
  const int b  = blockIdx.z;

  f32x16 acc[2][FN] = {};
  uint4 rA[4], rB[NB];

  #pragma unroll
  for (int r = 0; r < 4; ++r) {
    const int idx = t + r*256, row = idx >> 3, ch = idx & 7;
    rA[r] = *(const uint4*)&Wh[(size_t)(m0+row)*CIN + ch*8];
  }
  #pragma unroll
  for (int r = 0; r < NB; ++r) {
    const int idx = t + r*256, row = idx >> 3, ch = idx & 7;
    rB[r] = *(const uint4*)&Bt[((size_t)b*NTOT + n0 + row)*CIN + ch*8];
  }
  #pragma unroll
  for (int r = 0; r < 4; ++r) {
    const int idx = t + r*256, row = idx >> 3, ch = idx & 7;
    *(uint4*)&A_lds[0][row*64 + ((ch ^ (row&7))*8)] = rA[r];
  }
  #pragma unroll
  for (int r = 0; r < NB; ++r) {
    const int idx = t + r*256, row = idx >> 3, ch = idx & 7;
    *(uint4*)&B_lds[0][row*64 + ((ch ^ (row&7))*8)] = rB[r];
  }
  __syncthreads();

  for (int it = 0; it < 4; ++it) {
    const int cur = it & 1;
    if (it < 3) {
      const int c0 = (it+1)*64;
      #pragma unroll
      for (int r = 0; r < 4; ++r) {
        const int idx = t + r*256, row = idx >> 3, ch = idx & 7;
        rA[r] = *(const uint4*)&Wh[(size_t)(m0+row)*CIN + c0 + ch*8];
      }
      #pragma unroll
      for (int r = 0; r < NB; ++r) {
        const int idx = t + r*256, row = idx >> 3, ch = idx & 7;
        rB[r] = *(const uint4*)&Bt[((size_t)b*NTOT + n0 + row)*CIN + c0 + ch*8];
      }
    }
    #pragma unroll
    for (int ks = 0; ks < 4; ++ks) {
      const int ch = 2*ks + g;
      f16x8 a[2], bb[FN];
      #pragma unroll
      for (int fi = 0; fi < 2; ++fi) {
        const int row = wm*64 + fi*32 + nl;
        a[fi] = as_f16x8(*(const uint4*)&A_lds[cur][row*64 + ((ch ^ (row&7))*8)]);
      }
      #pragma unroll
      for (int fj = 0; fj < FN; ++fj) {
        const int row = wn*(BN/2) + fj*32 + nl;
        bb[fj] = as_f16x8(*(const uint4*)&B_lds[cur][row*64 + ((ch ^ (row&7))*8)]);
      }
      #pragma unroll
      for (int fi = 0; fi < 2; ++fi)
        #pragma unroll
        for (int fj = 0; fj < FN; ++fj)
          acc[fi][fj] = __builtin_amdgcn_mfma_f32_32x32x16_f16(a[fi], bb[fj], acc[fi][fj], 0, 0, 0);
    }
    if (it < 3) {
      #pragma unroll
      for (int r = 0; r < 4; ++r) {
        const int idx = t + r*256, row = idx >> 3, ch = idx & 7;
        *(uint4*)&A_lds[cur^1][row*64 + ((ch ^ (row&7))*8)] = rA[r];
      }
      #pragma unroll
      for (int r = 0; r < NB; ++r) {
        const int idx = t + r*256, row = idx >> 3, ch = idx & 7;
        *(uint4*)&B_lds[cur^1][row*64 + ((ch ^ (row&7))*8)] = rB[r];
      }
      __syncthreads();
    }
  }

  #pragma unroll
  for (int fi = 0; fi < 2; ++fi) {
    #pragma unroll
    for (int fj = 0; fj < FN; ++fj) {
      const int n = n0 + wn*(BN/2) + fj*32 + nl;
      #pragma unroll
      for (int q = 0; q < 4; ++q) {
        const int ob = m0 + wm*64 + fi*32 + 8*q + 4*g;
        const float v0 = acc[fi][fj][4*q+0] + ball[ob+0];
        const float v1 = acc[fi][fj][4*q+1] + ball[ob+1];
        const float v2 = acc[fi][fj][4*q+2] + ball[ob+2];
        const float v3 = acc[fi][fj][4*q+3] + ball[ob+3];
        if (MODE == 0) {
          if (ob < 128) {
            const int h = ob >> 4, k0 = ob & 15;
            ushort4 r; r.x = f2h(v0); r.y = f2h(v1); r.z = f2h(v2); r.w = f2h(v3);
            *(ushort4*)&q_t[(((size_t)b*NH + h)*NTOT + n)*KD + k0] = r;
          } else if (ob < 256) {
            const int oo = ob - 128;
            const int h = oo >> 4, k0 = oo & 15;
            const int plane = k0 >> 3, j0 = k0 & 7;
            ushort4 r; r.x = f2h(v0); r.y = f2h(v1); r.z = f2h(v2); r.w = f2h(v3);
            *(ushort4*)&k_t[((((size_t)b*NH + h)*2 + plane)*NTOT + n)*8 + j0] = r;
          } else {
            const int oo = ob - 256;
            const int h = oo >> 5, d0 = oo & 31;
            const int mb = n >> 4, loc = n & 15;
            const int g2 = (loc >> 2) & 1;
            const int j  = (loc & 3) + ((loc >> 3) << 2);
            u16* vp = v_h + (((((size_t)b*NH + h)*64 + mb)*2 + g2)*32 + d0)*8 + j;
            vp[0*8] = f2h(v0);
            vp[1*8] = f2h(v1);
            vp[2*8] = f2h(v2);
            vp[3*8] = f2h(v3);
          }
        } else {
          float* op = outp + ((size_t)b*CIN + ob)*NTOT + n;
          op[0*NTOT] = v0; op[1*NTOT] = v1; op[2*NTOT] = v2; op[3*NTOT] = v3;
        }
      }
    }
  }
}

__global__ __launch_bounds__(1024) void attn_mfma(
    const u16* __restrict__ Qt, const u16* __restrict__ Kt,
    const u16* __restrict__ Vt, u16* __restrict__ Ot)
{
  __shared__ u16 K_lds[2*NTOT*8];
  __shared__ u16 V_lds[4096*8];
  const int t    = threadIdx.x;
  const int lane = t & 63;
  const int wave = t >> 6;
  const int bh   = blockIdx.x >> 1;
  const int half = blockIdx.x & 1;
  const int g = lane >> 5, nl = lane & 31;
  const int n0 = half*512 + wave*32;

  const u16* Kh = Kt + (size_t)bh*(2*NTOT*8);
  const u16* Vh = Vt + (size_t)bh*(4096*8);
  const u16* Qh = Qt + (size_t)bh*(NTOT*KD);

  #pragma unroll
  for (int r = 0; r < 2; ++r) {
    const int uu = r*1024 + t;
    *(uint4*)&K_lds[uu*8] = *(const uint4*)&Kh[uu*8];
  }
  #pragma unroll
  for (int r = 0; r < 4; ++r) {
    const int uu = r*1024 + t;
    *(uint4*)&V_lds[uu*8] = *(const uint4*)&Vh[uu*8];
  }

  const f16x8 qf = as_f16x8(*(const uint4*)&Qh[(size_t)(n0+nl)*KD + g*8]);
  __syncthreads();

  const f32x16 fzero = {};
  f32x16 acc = {};
  float l0 = 0.f, l1 = 0.f, l2 = 0.f, l3 = 0.f;
  const char* Kb = (const char*)K_lds + g*16384 + nl*16;
  const char* Vb = (const char*)V_lds + g*512   + nl*16;

  f16x8 kf  = as_f16x8(*(const uint4*)(Kb));
  uint4 va0 = *(const uint4*)(Vb);
  uint4 va1 = *(const uint4*)(Vb + 1024);
  f32x16 s_cur = __builtin_amdgcn_mfma_f32_32x32x16_f16(kf, qf, fzero, 0, 0, 0);

  #pragma unroll 2
  for (int st = 0; st < 31; ++st) {
    const f16x8 kfn = as_f16x8(*(const uint4*)(Kb + (st+1)*512));
    __builtin_amdgcn_s_setprio(1);
    const f32x16 s_next = __builtin_amdgcn_mfma_f32_32x32x16_f16(kfn, qf, fzero, 0, 0, 0);
    __builtin_amdgcn_s_setprio(0);
    const uint4 nva0 = *(const uint4*)(Vb + (st+1)*2048);
    const uint4 nva1 = *(const uint4*)(Vb + (st+1)*2048 + 1024);
    {
      float p[8];
      #pragma unroll
      for (int r = 0; r < 8; ++r) p[r] = fexp2(s_cur[r]);
      uint4 pb0;
      pb0.x = pkrtz(p[0], p[1]); pb0.y = pkrtz(p[2], p[3]);
      pb0.z = pkrtz(p[4], p[5]); pb0.w = pkrtz(p[6], p[7]);
      l0 = dot2acc(pb0.x, l0); l1 = dot2acc(pb0.y, l1);
      l2 = dot2acc(pb0.z, l2); l3 = dot2acc(pb0.w, l3);
      __builtin_amdgcn_s_setprio(1);
      acc = __builtin_amdgcn_mfma_f32_32x32x16_f16(as_f16x8(va0), as_f16x8(pb0), acc, 0, 0, 0);
      __builtin_amdgcn_s_setprio(0);
    }
    {
      float p[8];
      #pragma unroll
      for (int r = 0; r < 8; ++r) p[r] = fexp2(s_cur[8+r]);
      uint4 pb1;
      pb1.x = pkrtz(p[0], p[1]); pb1.y = pkrtz(p[2], p[3]);
      pb1.z = pkrtz(p[4], p[5]); pb1.w = pkrtz(p[6], p[7]);
      l0 = dot2acc(pb1.x, l0); l1 = dot2acc(pb1.y, l1);
      l2 = dot2acc(pb1.z, l2); l3 = dot2acc(pb1.w, l3);
      __builtin_amdgcn_s_setprio(1);
      acc = __builtin_amdgcn_mfma_f32_32x32x16_f16(as_f16x8(va1), as_f16x8(pb1), acc, 0, 0, 0);
      __builtin_amdgcn_s_setprio(0);
    }
    s_cur = s_next; va0 = nva0; va1 = nva1;
  }
  {
    {
      float p[8];
      #pragma unroll
      for (int r = 0; r < 8; ++r) p[r] = fexp2(s_cur[r]);
      uint4 pb0;
      pb0.x = pkrtz(p[0], p[1]); pb0.y = pkrtz(p[2], p[3]);
      pb0.z = pkrtz(p[4], p[5]); pb0.w = pkrtz(p[6], p[7]);
      l0 = dot2acc(pb0.x, l0); l1 = dot2acc(pb0.y, l1);
      l2 = dot2acc(pb0.z, l2); l3 = dot2acc(pb0.w, l3);
      acc = __builtin_amdgcn_mfma_f32_32x32x16_f16(as_f16x8(va0), as_f16x8(pb0), acc, 0, 0, 0);
    }
    {
      float p[8];
      #pragma unroll
      for (int r = 0; r < 8; ++r) p[r] = fexp2(s_cur[8+r]);
      uint4 pb1;
      pb1.x = pkrtz(p[0], p[1]); pb1.y = pkrtz(p[2], p[3]);
      pb1.z = pkrtz(p[4], p[5]); pb1.w = pkrtz(p[6], p[7]);
      l0 = dot2acc(pb1.x, l0); l1 = dot2acc(pb1.y, l1);
      l2 = dot2acc(pb1.z, l2); l3 = dot2acc(pb1.w, l3);
      acc = __builtin_amdgcn_mfma_f32_32x32x16_f16(as_f16x8(va1), as_f16x8(pb1), acc, 0, 0, 0);
    }
  }

  const float lp = (l0 + l1) + (l2 + l3);
  const float lt = lp + __shfl_xor(lp, 32);
  const float rl = 1.0f / lt;
  const int b = bh >> 3, h = bh & 7;
  u16* op = Ot + ((size_t)b*NTOT + n0 + nl)*CIN + h*DV;
  #pragma unroll
  for (int q = 0; q < 4; ++q) {
    const float v0 = fmaxf(acc[4*q+0]*rl, 0.f);
    const float v1 = fmaxf(acc[4*q+1]*rl, 0.f);
    const float v2 = fmaxf(acc[4*q+2]*rl, 0.f);
    const float v3 = fmaxf(acc[4*q+3]*rl, 0.f);
    uint2 pk; pk.x = pkrtz(v0, v1); pk.y = pkrtz(v2, v3);
    *(uint2*)&op[8*q + 4*g] = pk;
  }
}

// ---------------------------------------------------------------------------
extern "C" void kernel_launch(void* const* d_in, const int* in_sizes, int n_in,
                              void* d_out, int out_size, void* d_ws, size_t ws_size,
                              hipStream_t stream) {
  const float* x  = (const float*)d_in[0];
  const float* wq = (const float*)d_in[1];
  const float* sq = (const float*)d_in[2];
  const float* bq = (const float*)d_in[3];
  const float* wk = (const float*)d_in[4];
  const float* sk = (const float*)d_in[5];
  const float* bk = (const float*)d_in[6];
  const float* wv = (const float*)d_in[7];
  const float* sv = (const float*)d_in[8];
  const float* bv = (const float*)d_in[9];
  const float* wp = (const float*)d_in[10];
  const float* sp = (const float*)d_in[11];
  const float* bp = (const float*)d_in[12];
  float* out = (float*)d_out;

  // ws: x_t/o_t overlay @0 (8MB) | q_t @8M | k_t @12M | v_h @16M (8MB) |
  //     wqkv @24M | wph | ball
  char* ws = (char*)d_ws;
  u16*   x_t  = (u16*)(ws);
  u16*   q_t  = (u16*)(ws + (8u  << 20));
  u16*   k_t  = (u16*)(ws + (12u << 20));
  u16*   v_h  = (u16*)(ws + (16u << 20));
  u16*   wqkv = (u16*)(ws + (24u << 20));
  u16*   wph  = (u16*)(ws + (24u << 20) + (256u << 10));
  float* ball = (float*)(ws + (24u << 20) + (384u << 10));

  void* ka[] = { (void*)&x,
                 (void*)&wq, (void*)&sq, (void*)&bq,
                 (void*)&wk, (void*)&sk, (void*)&bk,
                 (void*)&wv, (void*)&sv, (void*)&bv,
                 (void*)&wp, (void*)&sp, (void*)&bp,
                 (void*)&x_t, (void*)&q_t, (void*)&k_t, (void*)&v_h,
                 (void*)&wqkv, (void*)&wph, (void*)&ball, (void*)&out };
  hipError_t err = hipLaunchCooperativeKernel(
      (void*)mega, dim3(256), dim3(1024), ka, 0, stream);

  if (err != hipSuccess) {
    (void)hipGetLastError();   // clear; deterministic fallback: R10 4-kernel path
    prep_fused<<<dim3(1216), dim3(256), 0, stream>>>(
        x, x_t, wq, sq, bq, wk, sk, bk, wv, sv, bv, wp, sp, bp, wqkv, wph, ball);
    conv_mfma<128, 0><<<dim3(8, 4, 16), dim3(256), 0, stream>>>(
        wqkv, x_t, ball, q_t, k_t, v_h, nullptr);
    attn_mfma<<<dim3(256), dim3(1024), 0, stream>>>(q_t, k_t, v_h, x_t);
    conv_mfma<64, 1><<<dim3(16, 2, 16), dim3(256), 0, stream>>>(
        wph, x_t, ball + 512, nullptr, nullptr, nullptr, out);
  }
}

// Round 12
// 154.221 us; speedup vs baseline: 1.1749x; 1.1749x over previous
//
#include <hip/hip_runtime.h>

#define NTOT 1024
#define CIN  256
#define BATCH 16
#define NH   8
#define KD   16
#define DV   32
#define L2E  1.44269504088896340736f

typedef unsigned short u16;
typedef unsigned int   u32;
typedef __attribute__((ext_vector_type(2)))  _Float16 f16x2;
typedef __attribute__((ext_vector_type(8)))  _Float16 f16x8;
typedef __attribute__((ext_vector_type(16))) float    f32x16;

__device__ inline f16x8 as_f16x8(uint4 u) { return __builtin_bit_cast(f16x8, u); }
__device__ inline f16x2 as_f16x2(u32 u)   { return __builtin_bit_cast(f16x2, u); }
__device__ inline u32 pkrtz(float a, float b) {
  return __builtin_bit_cast(u32, __builtin_amdgcn_cvt_pkrtz(a, b));
}
__device__ inline u16 f2h(float x) {
  return __builtin_bit_cast(u16, (_Float16)x);
}
__device__ inline float fexp2(float x) {
#if __has_builtin(__builtin_amdgcn_exp2f)
  return __builtin_amdgcn_exp2f(x);              // raw v_exp_f32
#else
  float r; asm("v_exp_f32 %0, %1" : "=v"(r) : "v"(x)); return r;
#endif
}
__device__ inline float dot2acc(u32 p2, float c) {
#if __has_builtin(__builtin_amdgcn_fdot2)
  const f16x2 one2 = __builtin_bit_cast(f16x2, (u32)0x3C003C00u);
  return __builtin_amdgcn_fdot2(as_f16x2(p2), one2, c, false);
#else
  const f16x2 v = as_f16x2(p2);
  return c + (float)v[0] + (float)v[1];
#endif
}

// ---------------------------------------------------------------------------
// Fused prep: blocks [0,1024): x[b][c][n] fp32 -> x_t[b][n][c] fp16 (64x64
// LDS transpose).  Blocks [1024,1216): weight fp32->fp16 with BN scale folded
// (Q rows x log2e for exp2-domain softmax), 4 rows per block.
// ---------------------------------------------------------------------------
__global__ __launch_bounds__(256) void prep_fused(
    const float* __restrict__ X, u16* __restrict__ Xt,
    const float* __restrict__ wq, const float* __restrict__ sq, const float* __restrict__ bq,
    const float* __restrict__ wk, const float* __restrict__ sk, const float* __restrict__ bk,
    const float* __restrict__ wv, const float* __restrict__ sv, const float* __restrict__ bv,
    const float* __restrict__ wp, const float* __restrict__ sp, const float* __restrict__ bp,
    u16* __restrict__ wqkv, u16* __restrict__ wph, float* __restrict__ ball)
{
  __shared__ u16 T[64][64];
  const int bx = blockIdx.x;
  const int t  = threadIdx.x;
  if (bx < 1024) {
    const int n0 = (bx & 15) * 64;
    const int c0 = ((bx >> 4) & 3) * 64;
    const int b  = bx >> 6;
    #pragma unroll
    for (int rr = 0; rr < 4; ++rr) {
      const int c  = rr*16 + (t>>4);
      const int n4 = (t&15)*4;
      const float4 v = *(const float4*)&X[((size_t)b*CIN + c0 + c)*NTOT + n0 + n4];
      ushort4 r; r.x=f2h(v.x); r.y=f2h(v.y); r.z=f2h(v.z); r.w=f2h(v.w);
      *(ushort4*)&T[c][n4] = r;
    }
    __syncthreads();
    const int nl = t & 63;
    #pragma unroll
    for (int j = 0; j < 2; ++j) {
      const int oct = (t>>6)*2 + j;
      uint4 w;
      w.x = (u32)T[oct*8+0][nl] | ((u32)T[oct*8+1][nl] << 16);
      w.y = (u32)T[oct*8+2][nl] | ((u32)T[oct*8+3][nl] << 16);
      w.z = (u32)T[oct*8+4][nl] | ((u32)T[oct*8+5][nl] << 16);
      w.w = (u32)T[oct*8+6][nl] | ((u32)T[oct*8+7][nl] << 16);
      *(uint4*)&Xt[((size_t)b*NTOT + n0 + nl)*CIN + c0 + oct*8] = w;
    }
  } else {
    const int row = (bx - 1024)*4 + (t>>6);   // 0..767
    const int ln  = t & 63;
    const float* src; u16* dst; float sc, bi;
    if (row < 128)      { src = wq + (size_t)row*CIN;       sc = sq[row]*L2E;     bi = bq[row]*L2E;     dst = wqkv + (size_t)row*CIN; }
    else if (row < 256) { src = wk + (size_t)(row-128)*CIN; sc = sk[row-128];     bi = bk[row-128];     dst = wqkv + (size_t)row*CIN; }
    else if (row < 512) { src = wv + (size_t)(row-256)*CIN; sc = sv[row-256];     bi = bv[row-256];     dst = wqkv + (size_t)row*CIN; }
    else                { src = wp + (size_t)(row-512)*CIN; sc = sp[row-512];     bi = bp[row-512];     dst = wph + (size_t)(row-512)*CIN; }
    const float4 v = *(const float4*)&src[ln*4];
    ushort4 r;
    r.x = f2h(v.x*sc); r.y = f2h(v.y*sc); r.z = f2h(v.z*sc); r.w = f2h(v.w*sc);
    *(ushort4*)&dst[ln*4] = r;
    if (ln == 0) ball[row] = bi;
  }
}

// ---------------------------------------------------------------------------
// fp16 MFMA GEMM, BM=128, BN templated, 4 waves 2x2, double-buffered LDS
// (reg-staged).  MODE 0 epilogue -> attention-native layouts.  MODE 1 -> fp32.
// ---------------------------------------------------------------------------
template<int BN, int MODE>
__global__ __launch_bounds__(256) void conv_mfma(
    const u16* __restrict__ Wh, const u16* __restrict__ Bt,
    const float* __restrict__ ball,
    u16* __restrict__ q_t, u16* __restrict__ k_t, u16* __restrict__ v_h,
    float* __restrict__ outp)
{
  constexpr int FN = BN / 64;
  constexpr int NB = BN / 32;
  __shared__ u16 A_lds[2][128 * 64];
  __shared__ u16 B_lds[2][BN * 64];
  const int t    = threadIdx.x;
  const int lane = t & 63;
  const int w    = t >> 6;
  const int wm = w >> 1, wn = w & 1;
  const int g = lane >> 5, nl = lane & 31;
  const int n0 = blockIdx.x * BN;
  const int m0 = blockIdx.y * 128;
  const int b  = blockIdx.z;

  f32x16 acc[2][FN] = {};
  uint4 rA[4], rB[NB];

  #pragma unroll
  for (int r = 0; r < 4; ++r) {
    const int idx = t + r*256, row = idx >> 3, ch = idx & 7;
    rA[r] = *(const uint4*)&Wh[(size_t)(m0+row)*CIN + ch*8];
  }
  #pragma unroll
  for (int r = 0; r < NB; ++r) {
    const int idx = t + r*256, row = idx >> 3, ch = idx & 7;
    rB[r] = *(const uint4*)&Bt[((size_t)b*NTOT + n0 + row)*CIN + ch*8];
  }
  #pragma unroll
  for (int r = 0; r < 4; ++r) {
    const int idx = t + r*256, row = idx >> 3, ch = idx & 7;
    *(uint4*)&A_lds[0][row*64 + ((ch ^ (row&7))*8)] = rA[r];
  }
  #pragma unroll
  for (int r = 0; r < NB; ++r) {
    const int idx = t + r*256, row = idx >> 3, ch = idx & 7;
    *(uint4*)&B_lds[0][row*64 + ((ch ^ (row&7))*8)] = rB[r];
  }
  __syncthreads();

  for (int it = 0; it < 4; ++it) {
    const int cur = it & 1;
    if (it < 3) {
      const int c0 = (it+1)*64;
      #pragma unroll
      for (int r = 0; r < 4; ++r) {
        const int idx = t + r*256, row = idx >> 3, ch = idx & 7;
        rA[r] = *(const uint4*)&Wh[(size_t)(m0+row)*CIN + c0 + ch*8];
      }
      #pragma unroll
      for (int r = 0; r < NB; ++r) {
        const int idx = t + r*256, row = idx >> 3, ch = idx & 7;
        rB[r] = *(const uint4*)&Bt[((size_t)b*NTOT + n0 + row)*CIN + c0 + ch*8];
      }
    }
    #pragma unroll
    for (int ks = 0; ks < 4; ++ks) {
      const int ch = 2*ks + g;
      f16x8 a[2], bb[FN];
      #pragma unroll
      for (int fi = 0; fi < 2; ++fi) {
        const int row = wm*64 + fi*32 + nl;
        a[fi] = as_f16x8(*(const uint4*)&A_lds[cur][row*64 + ((ch ^ (row&7))*8)]);
      }
      #pragma unroll
      for (int fj = 0; fj < FN; ++fj) {
        const int row = wn*(BN/2) + fj*32 + nl;
        bb[fj] = as_f16x8(*(const uint4*)&B_lds[cur][row*64 + ((ch ^ (row&7))*8)]);
      }
      #pragma unroll
      for (int fi = 0; fi < 2; ++fi)
        #pragma unroll
        for (int fj = 0; fj < FN; ++fj)
          acc[fi][fj] = __builtin_amdgcn_mfma_f32_32x32x16_f16(a[fi], bb[fj], acc[fi][fj], 0, 0, 0);
    }
    if (it < 3) {
      #pragma unroll
      for (int r = 0; r < 4; ++r) {
        const int idx = t + r*256, row = idx >> 3, ch = idx & 7;
        *(uint4*)&A_lds[cur^1][row*64 + ((ch ^ (row&7))*8)] = rA[r];
      }
      #pragma unroll
      for (int r = 0; r < NB; ++r) {
        const int idx = t + r*256, row = idx >> 3, ch = idx & 7;
        *(uint4*)&B_lds[cur^1][row*64 + ((ch ^ (row&7))*8)] = rB[r];
      }
      __syncthreads();
    }
  }

  #pragma unroll
  for (int fi = 0; fi < 2; ++fi) {
    #pragma unroll
    for (int fj = 0; fj < FN; ++fj) {
      const int n = n0 + wn*(BN/2) + fj*32 + nl;
      #pragma unroll
      for (int q = 0; q < 4; ++q) {
        const int ob = m0 + wm*64 + fi*32 + 8*q + 4*g;   // wave-uniform
        const float v0 = acc[fi][fj][4*q+0] + ball[ob+0];
        const float v1 = acc[fi][fj][4*q+1] + ball[ob+1];
        const float v2 = acc[fi][fj][4*q+2] + ball[ob+2];
        const float v3 = acc[fi][fj][4*q+3] + ball[ob+3];
        if (MODE == 0) {
          if (ob < 128) {                       // Q rows
            const int h = ob >> 4, k0 = ob & 15;
            ushort4 r; r.x = f2h(v0); r.y = f2h(v1); r.z = f2h(v2); r.w = f2h(v3);
            *(ushort4*)&q_t[(((size_t)b*NH + h)*NTOT + n)*KD + k0] = r;
          } else if (ob < 256) {                // K rows -> plane layout
            const int oo = ob - 128;
            const int h = oo >> 4, k0 = oo & 15;
            const int plane = k0 >> 3, j0 = k0 & 7;
            ushort4 r; r.x = f2h(v0); r.y = f2h(v1); r.z = f2h(v2); r.w = f2h(v3);
            *(ushort4*)&k_t[((((size_t)b*NH + h)*2 + plane)*NTOT + n)*8 + j0] = r;
          } else {                              // V rows -> permuted layout
            const int oo = ob - 256;
            const int h = oo >> 5, d0 = oo & 31;
            const int mb = n >> 4, loc = n & 15;
            const int g2 = (loc >> 2) & 1;
            const int j  = (loc & 3) + ((loc >> 3) << 2);
            u16* vp = v_h + (((((size_t)b*NH + h)*64 + mb)*2 + g2)*32 + d0)*8 + j;
            vp[0*8] = f2h(v0);
            vp[1*8] = f2h(v1);
            vp[2*8] = f2h(v2);
            vp[3*8] = f2h(v3);
          }
        } else {
          float* op = outp + ((size_t)b*CIN + ob)*NTOT + n;
          op[0*NTOT] = v0; op[1*NTOT] = v1; op[2*NTOT] = v2; op[3*NTOT] = v3;
        }
      }
    }
  }
}

// ---------------------------------------------------------------------------
// fp16 MFMA attention (R10 base + WAVE-PHASE STAGGERING): exp2 domain, no
// max-tracking (so K-step order is free), shuffle-free P->PV, 16 waves = one
// (b,h) x 512 queries, 96 KB LDS, one-step-ahead QK rotation.
// Each wave starts its 32-step K sweep at phase pr = (w + (w>>2)) & 3
// (8-step granularity), so the 4 waves of a SIMD are out of phase and their
// exp bursts overlap other waves' MFMA/pack/LDS stretches instead of
// colliding on the trans pipe.  acc/l are order-independent sums.
// ---------------------------------------------------------------------------
__global__ __launch_bounds__(1024) void attn_mfma(
    const u16* __restrict__ Qt,  // [bh][n][16] fp16 (x log2e folded)
    const u16* __restrict__ Kt,  // [bh][plane2][m][8] fp16
    const u16* __restrict__ Vt,  // [bh][mb16][g2][d32][8] fp16
    u16* __restrict__ Ot)        // [b][n][256c] fp16 (relu'd)
{
  __shared__ u16 K_lds[2*NTOT*8];   // 32 KB
  __shared__ u16 V_lds[4096*8];     // 64 KB
  const int t    = threadIdx.x;
  const int lane = t & 63;
  const int wave = t >> 6;
  const int bh   = blockIdx.x >> 1;
  const int half = blockIdx.x & 1;
  const int g = lane >> 5, nl = lane & 31;
  const int n0 = half*512 + wave*32;

  const u16* Kh = Kt + (size_t)bh*(2*NTOT*8);
  const u16* Vh = Vt + (size_t)bh*(4096*8);
  const u16* Qh = Qt + (size_t)bh*(NTOT*KD);

  #pragma unroll
  for (int r = 0; r < 2; ++r) {
    const int uu = r*1024 + t;
    *(uint4*)&K_lds[uu*8] = *(const uint4*)&Kh[uu*8];
  }
  #pragma unroll
  for (int r = 0; r < 4; ++r) {
    const int uu = r*1024 + t;
    *(uint4*)&V_lds[uu*8] = *(const uint4*)&Vh[uu*8];
  }

  const f16x8 qf = as_f16x8(*(const uint4*)&Qh[(size_t)(n0+nl)*KD + g*8]);
  __syncthreads();

  const f32x16 fzero = {};
  f32x16 acc = {};
  float l0 = 0.f, l1 = 0.f, l2 = 0.f, l3 = 0.f;
  const char* Kb = (const char*)K_lds + g*16384 + nl*16;  // + step*512
  const char* Vb = (const char*)V_lds + g*512   + nl*16;  // + step*2048 (+1024)

  // wave-phase rotation: phase covers 8 steps; pr spreads 0..3 across the
  // waves of a SIMD under either wave->SIMD mapping (w>>2 or w&3).
  const int pr = (wave + (wave >> 2)) & 3;

  // prologue: first step of the rotated sequence = pr*8
  f16x8 kf  = as_f16x8(*(const uint4*)(Kb + pr*4096));
  uint4 va0 = *(const uint4*)(Vb + pr*16384);
  uint4 va1 = *(const uint4*)(Vb + pr*16384 + 1024);
  f32x16 s_cur = __builtin_amdgcn_mfma_f32_32x32x16_f16(kf, qf, fzero, 0, 0, 0);

  for (int j = 0; j < 4; ++j) {                     // 4 phases in rotated order
    const char* kp  = Kb + ((pr + j) & 3) * 4096;
    const char* vp  = Vb + ((pr + j) & 3) * 16384;
    const char* kpn = Kb + ((pr + j + 1) & 3) * 4096;
    const char* vpn = Vb + ((pr + j + 1) & 3) * 16384;
    #pragma unroll
    for (int sl = 0; sl < 8; ++sl) {                // 8 steps per phase
      f16x8 kfn; uint4 nva0, nva1; f32x16 s_next;
      bool adv = true;
      if (sl < 7) {
        kfn = as_f16x8(*(const uint4*)(kp + (sl+1)*512));
        __builtin_amdgcn_s_setprio(1);
        s_next = __builtin_amdgcn_mfma_f32_32x32x16_f16(kfn, qf, fzero, 0, 0, 0);
        __builtin_amdgcn_s_setprio(0);
        nva0 = *(const uint4*)(vp + (sl+1)*2048);
        nva1 = *(const uint4*)(vp + (sl+1)*2048 + 1024);
      } else if (j < 3) {                           // cross into next phase
        kfn = as_f16x8(*(const uint4*)(kpn));
        __builtin_amdgcn_s_setprio(1);
        s_next = __builtin_amdgcn_mfma_f32_32x32x16_f16(kfn, qf, fzero, 0, 0, 0);
        __builtin_amdgcn_s_setprio(0);
        nva0 = *(const uint4*)(vpn);
        nva1 = *(const uint4*)(vpn + 1024);
      } else {
        adv = false;                                // very last step: no prefetch
      }

      // ---- half 0: m-slots 0..7 ----
      {
        float p[8];
        #pragma unroll
        for (int r = 0; r < 8; ++r) p[r] = fexp2(s_cur[r]);
        uint4 pb0;
        pb0.x = pkrtz(p[0], p[1]); pb0.y = pkrtz(p[2], p[3]);
        pb0.z = pkrtz(p[4], p[5]); pb0.w = pkrtz(p[6], p[7]);
        l0 = dot2acc(pb0.x, l0); l1 = dot2acc(pb0.y, l1);
        l2 = dot2acc(pb0.z, l2); l3 = dot2acc(pb0.w, l3);
        __builtin_amdgcn_s_setprio(1);
        acc = __builtin_amdgcn_mfma_f32_32x32x16_f16(as_f16x8(va0), as_f16x8(pb0), acc, 0, 0, 0);
        __builtin_amdgcn_s_setprio(0);
      }
      // ---- half 1: m-slots 8..15 ----
      {
        float p[8];
        #pragma unroll
        for (int r = 0; r < 8; ++r) p[r] = fexp2(s_cur[8+r]);
        uint4 pb1;
        pb1.x = pkrtz(p[0], p[1]); pb1.y = pkrtz(p[2], p[3]);
        pb1.z = pkrtz(p[4], p[5]); pb1.w = pkrtz(p[6], p[7]);
        l0 = dot2acc(pb1.x, l0); l1 = dot2acc(pb1.y, l1);
        l2 = dot2acc(pb1.z, l2); l3 = dot2acc(pb1.w, l3);
        __builtin_amdgcn_s_setprio(1);
        acc = __builtin_amdgcn_mfma_f32_32x32x16_f16(as_f16x8(va1), as_f16x8(pb1), acc, 0, 0, 0);
        __builtin_amdgcn_s_setprio(0);
      }
      if (adv) { s_cur = s_next; va0 = nva0; va1 = nva1; }
    }
  }

  const float lp = (l0 + l1) + (l2 + l3);
  const float lt = lp + __shfl_xor(lp, 32);
  const float rl = 1.0f / lt;
  const int b = bh >> 3, h = bh & 7;
  u16* op = Ot + ((size_t)b*NTOT + n0 + nl)*CIN + h*DV;
  #pragma unroll
  for (int q = 0; q < 4; ++q) {
    const float v0 = fmaxf(acc[4*q+0]*rl, 0.f);
    const float v1 = fmaxf(acc[4*q+1]*rl, 0.f);
    const float v2 = fmaxf(acc[4*q+2]*rl, 0.f);
    const float v3 = fmaxf(acc[4*q+3]*rl, 0.f);
    uint2 pk; pk.x = pkrtz(v0, v1); pk.y = pkrtz(v2, v3);
    *(uint2*)&op[8*q + 4*g] = pk;   // c = h*32 + 8q + 4g + {0..3}
  }
}

// ---------------------------------------------------------------------------
extern "C" void kernel_launch(void* const* d_in, const int* in_sizes, int n_in,
                              void* d_out, int out_size, void* d_ws, size_t ws_size,
                              hipStream_t stream) {
  const float* x  = (const float*)d_in[0];
  const float* wq = (const float*)d_in[1];
  const float* sq = (const float*)d_in[2];
  const float* bq = (const float*)d_in[3];
  const float* wk = (const float*)d_in[4];
  const float* sk = (const float*)d_in[5];
  const float* bk = (const float*)d_in[6];
  const float* wv = (const float*)d_in[7];
  const float* sv = (const float*)d_in[8];
  const float* bv = (const float*)d_in[9];
  const float* wp = (const float*)d_in[10];
  const float* sp = (const float*)d_in[11];
  const float* bp = (const float*)d_in[12];
  float* out = (float*)d_out;

  // ws: x_t/o_t overlay @0 (8MB) | q_t @8M | k_t @12M | v_h @16M (8MB) |
  //     wqkv @24M | wph | ball
  char* ws = (char*)d_ws;
  u16*   x_t  = (u16*)(ws);
  u16*   q_t  = (u16*)(ws + (8u  << 20));
  u16*   k_t  = (u16*)(ws + (12u << 20));
  u16*   v_h  = (u16*)(ws + (16u << 20));
  u16*   wqkv = (u16*)(ws + (24u << 20));
  u16*   wph  = (u16*)(ws + (24u << 20) + (256u << 10));
  float* ball = (float*)(ws + (24u << 20) + (384u << 10));

  prep_fused<<<dim3(1216), dim3(256), 0, stream>>>(
      x, x_t, wq, sq, bq, wk, sk, bk, wv, sv, bv, wp, sp, bp, wqkv, wph, ball);
  conv_mfma<128, 0><<<dim3(8, 4, 16), dim3(256), 0, stream>>>(
      wqkv, x_t, ball, q_t, k_t, v_h, nullptr);
  attn_mfma<<<dim3(256), dim3(1024), 0, stream>>>(q_t, k_t, v_h, x_t /* o_t */);
  conv_mfma<64, 1><<<dim3(16, 2, 16), dim3(256), 0, stream>>>(
      wph, x_t /* o_t */, ball + 512, nullptr, nullptr, nullptr, out);
}

// Round 13
// 58.446 us; speedup vs baseline: 3.1002x; 2.6387x over previous
//
#include <hip/hip_runtime.h>

#define NTOT 1024
#define CIN  256
#define BATCH 16
#define NH   8
#define KD   16
#define DV   32
#define L2E  1.44269504088896340736f

typedef unsigned short u16;
typedef unsigned int   u32;
typedef __attribute__((ext_vector_type(2)))  _Float16 f16x2;
typedef __attribute__((ext_vector_type(8)))  _Float16 f16x8;
typedef __attribute__((ext_vector_type(16))) float    f32x16;

__device__ inline f16x8 as_f16x8(uint4 u) { return __builtin_bit_cast(f16x8, u); }
__device__ inline f16x2 as_f16x2(u32 u)   { return __builtin_bit_cast(f16x2, u); }
__device__ inline u32 pkrtz(float a, float b) {
  return __builtin_bit_cast(u32, __builtin_amdgcn_cvt_pkrtz(a, b));
}
__device__ inline u16 f2h(float x) {
  return __builtin_bit_cast(u16, (_Float16)x);
}
__device__ inline float fexp2(float x) {
#if __has_builtin(__builtin_amdgcn_exp2f)
  return __builtin_amdgcn_exp2f(x);              // raw v_exp_f32
#else
  float r; asm("v_exp_f32 %0, %1" : "=v"(r) : "v"(x)); return r;
#endif
}
__device__ inline float dot2acc(u32 p2, float c) {
#if __has_builtin(__builtin_amdgcn_fdot2)
  const f16x2 one2 = __builtin_bit_cast(f16x2, (u32)0x3C003C00u);
  return __builtin_amdgcn_fdot2(as_f16x2(p2), one2, c, false);
#else
  const f16x2 v = as_f16x2(p2);
  return c + (float)v[0] + (float)v[1];
#endif
}

// ---------------------------------------------------------------------------
// Fused prep: blocks [0,1024): x[b][c][n] fp32 -> x_t[b][n][c] fp16 (64x64
// LDS transpose).  Blocks [1024,1216): weight fp32->fp16 with BN scale folded
// (Q rows x log2e for exp2-domain softmax), 4 rows per block.
// ---------------------------------------------------------------------------
__global__ __launch_bounds__(256) void prep_fused(
    const float* __restrict__ X, u16* __restrict__ Xt,
    const float* __restrict__ wq, const float* __restrict__ sq, const float* __restrict__ bq,
    const float* __restrict__ wk, const float* __restrict__ sk, const float* __restrict__ bk,
    const float* __restrict__ wv, const float* __restrict__ sv, const float* __restrict__ bv,
    const float* __restrict__ wp, const float* __restrict__ sp, const float* __restrict__ bp,
    u16* __restrict__ wqkv, u16* __restrict__ wph, float* __restrict__ ball)
{
  __shared__ u16 T[64][64];
  const int bx = blockIdx.x;
  const int t  = threadIdx.x;
  if (bx < 1024) {
    const int n0 = (bx & 15) * 64;
    const int c0 = ((bx >> 4) & 3) * 64;
    const int b  = bx >> 6;
    #pragma unroll
    for (int rr = 0; rr < 4; ++rr) {
      const int c  = rr*16 + (t>>4);
      const int n4 = (t&15)*4;
      const float4 v = *(const float4*)&X[((size_t)b*CIN + c0 + c)*NTOT + n0 + n4];
      ushort4 r; r.x=f2h(v.x); r.y=f2h(v.y); r.z=f2h(v.z); r.w=f2h(v.w);
      *(ushort4*)&T[c][n4] = r;
    }
    __syncthreads();
    const int nl = t & 63;
    #pragma unroll
    for (int j = 0; j < 2; ++j) {
      const int oct = (t>>6)*2 + j;
      uint4 w;
      w.x = (u32)T[oct*8+0][nl] | ((u32)T[oct*8+1][nl] << 16);
      w.y = (u32)T[oct*8+2][nl] | ((u32)T[oct*8+3][nl] << 16);
      w.z = (u32)T[oct*8+4][nl] | ((u32)T[oct*8+5][nl] << 16);
      w.w = (u32)T[oct*8+6][nl] | ((u32)T[oct*8+7][nl] << 16);
      *(uint4*)&Xt[((size_t)b*NTOT + n0 + nl)*CIN + c0 + oct*8] = w;
    }
  } else {
    const int row = (bx - 1024)*4 + (t>>6);   // 0..767
    const int ln  = t & 63;
    const float* src; u16* dst; float sc, bi;
    if (row < 128)      { src = wq + (size_t)row*CIN;       sc = sq[row]*L2E;     bi = bq[row]*L2E;     dst = wqkv + (size_t)row*CIN; }
    else if (row < 256) { src = wk + (size_t)(row-128)*CIN; sc = sk[row-128];     bi = bk[row-128];     dst = wqkv + (size_t)row*CIN; }
    else if (row < 512) { src = wv + (size_t)(row-256)*CIN; sc = sv[row-256];     bi = bv[row-256];     dst = wqkv + (size_t)row*CIN; }
    else                { src = wp + (size_t)(row-512)*CIN; sc = sp[row-512];     bi = bp[row-512];     dst = wph + (size_t)(row-512)*CIN; }
    const float4 v = *(const float4*)&src[ln*4];
    ushort4 r;
    r.x = f2h(v.x*sc); r.y = f2h(v.y*sc); r.z = f2h(v.z*sc); r.w = f2h(v.w*sc);
    *(ushort4*)&dst[ln*4] = r;
    if (ln == 0) ball[row] = bi;
  }
}

// ---------------------------------------------------------------------------
// fp16 MFMA GEMM, BM=128, BN templated, 4 waves 2x2, double-buffered LDS
// (reg-staged).  MODE 0 epilogue -> attention-native layouts.  MODE 1 -> fp32.
// ---------------------------------------------------------------------------
template<int BN, int MODE>
__global__ __launch_bounds__(256) void conv_mfma(
    const u16* __restrict__ Wh, const u16* __restrict__ Bt,
    const float* __restrict__ ball,
    u16* __restrict__ q_t, u16* __restrict__ k_t, u16* __restrict__ v_h,
    float* __restrict__ outp)
{
  constexpr int FN = BN / 64;
  constexpr int NB = BN / 32;
  __shared__ u16 A_lds[2][128 * 64];
  __shared__ u16 B_lds[2][BN * 64];
  const int t    = threadIdx.x;
  const int lane = t & 63;
  const int w    = t >> 6;
  const int wm = w >> 1, wn = w & 1;
  const int g = lane >> 5, nl = lane & 31;
  const int n0 = blockIdx.x * BN;
  const int m0 = blockIdx.y * 128;
  const int b  = blockIdx.z;

  f32x16 acc[2][FN] = {};
  uint4 rA[4], rB[NB];

  #pragma unroll
  for (int r = 0; r < 4; ++r) {
    const int idx = t + r*256, row = idx >> 3, ch = idx & 7;
    rA[r] = *(const uint4*)&Wh[(size_t)(m0+row)*CIN + ch*8];
  }
  #pragma unroll
  for (int r = 0; r < NB; ++r) {
    const int idx = t + r*256, row = idx >> 3, ch = idx & 7;
    rB[r] = *(const uint4*)&Bt[((size_t)b*NTOT + n0 + row)*CIN + ch*8];
  }
  #pragma unroll
  for (int r = 0; r < 4; ++r) {
    const int idx = t + r*256, row = idx >> 3, ch = idx & 7;
    *(uint4*)&A_lds[0][row*64 + ((ch ^ (row&7))*8)] = rA[r];
  }
  #pragma unroll
  for (int r = 0; r < NB; ++r) {
    const int idx = t + r*256, row = idx >> 3, ch = idx & 7;
    *(uint4*)&B_lds[0][row*64 + ((ch ^ (row&7))*8)] = rB[r];
  }
  __syncthreads();

  for (int it = 0; it < 4; ++it) {
    const int cur = it & 1;
    if (it < 3) {
      const int c0 = (it+1)*64;
      #pragma unroll
      for (int r = 0; r < 4; ++r) {
        const int idx = t + r*256, row = idx >> 3, ch = idx & 7;
        rA[r] = *(const uint4*)&Wh[(size_t)(m0+row)*CIN + c0 + ch*8];
      }
      #pragma unroll
      for (int r = 0; r < NB; ++r) {
        const int idx = t + r*256, row = idx >> 3, ch = idx & 7;
        rB[r] = *(const uint4*)&Bt[((size_t)b*NTOT + n0 + row)*CIN + c0 + ch*8];
      }
    }
    #pragma unroll
    for (int ks = 0; ks < 4; ++ks) {
      const int ch = 2*ks + g;
      f16x8 a[2], bb[FN];
      #pragma unroll
      for (int fi = 0; fi < 2; ++fi) {
        const int row = wm*64 + fi*32 + nl;
        a[fi] = as_f16x8(*(const uint4*)&A_lds[cur][row*64 + ((ch ^ (row&7))*8)]);
      }
      #pragma unroll
      for (int fj = 0; fj < FN; ++fj) {
        const int row = wn*(BN/2) + fj*32 + nl;
        bb[fj] = as_f16x8(*(const uint4*)&B_lds[cur][row*64 + ((ch ^ (row&7))*8)]);
      }
      #pragma unroll
      for (int fi = 0; fi < 2; ++fi)
        #pragma unroll
        for (int fj = 0; fj < FN; ++fj)
          acc[fi][fj] = __builtin_amdgcn_mfma_f32_32x32x16_f16(a[fi], bb[fj], acc[fi][fj], 0, 0, 0);
    }
    if (it < 3) {
      #pragma unroll
      for (int r = 0; r < 4; ++r) {
        const int idx = t + r*256, row = idx >> 3, ch = idx & 7;
        *(uint4*)&A_lds[cur^1][row*64 + ((ch ^ (row&7))*8)] = rA[r];
      }
      #pragma unroll
      for (int r = 0; r < NB; ++r) {
        const int idx = t + r*256, row = idx >> 3, ch = idx & 7;
        *(uint4*)&B_lds[cur^1][row*64 + ((ch ^ (row&7))*8)] = rB[r];
      }
      __syncthreads();
    }
  }

  #pragma unroll
  for (int fi = 0; fi < 2; ++fi) {
    #pragma unroll
    for (int fj = 0; fj < FN; ++fj) {
      const int n = n0 + wn*(BN/2) + fj*32 + nl;
      #pragma unroll
      for (int q = 0; q < 4; ++q) {
        const int ob = m0 + wm*64 + fi*32 + 8*q + 4*g;   // wave-uniform
        const float v0 = acc[fi][fj][4*q+0] + ball[ob+0];
        const float v1 = acc[fi][fj][4*q+1] + ball[ob+1];
        const float v2 = acc[fi][fj][4*q+2] + ball[ob+2];
        const float v3 = acc[fi][fj][4*q+3] + ball[ob+3];
        if (MODE == 0) {
          if (ob < 128) {                       // Q rows
            const int h = ob >> 4, k0 = ob & 15;
            ushort4 r; r.x = f2h(v0); r.y = f2h(v1); r.z = f2h(v2); r.w = f2h(v3);
            *(ushort4*)&q_t[(((size_t)b*NH + h)*NTOT + n)*KD + k0] = r;
          } else if (ob < 256) {                // K rows -> plane layout
            const int oo = ob - 128;
            const int h = oo >> 4, k0 = oo & 15;
            const int plane = k0 >> 3, j0 = k0 & 7;
            ushort4 r; r.x = f2h(v0); r.y = f2h(v1); r.z = f2h(v2); r.w = f2h(v3);
            *(ushort4*)&k_t[((((size_t)b*NH + h)*2 + plane)*NTOT + n)*8 + j0] = r;
          } else {                              // V rows -> permuted layout
            const int oo = ob - 256;
            const int h = oo >> 5, d0 = oo & 31;
            const int mb = n >> 4, loc = n & 15;
            const int g2 = (loc >> 2) & 1;
            const int j  = (loc & 3) + ((loc >> 3) << 2);
            u16* vp = v_h + (((((size_t)b*NH + h)*64 + mb)*2 + g2)*32 + d0)*8 + j;
            vp[0*8] = f2h(v0);
            vp[1*8] = f2h(v1);
            vp[2*8] = f2h(v2);
            vp[3*8] = f2h(v3);
          }
        } else {
          float* op = outp + ((size_t)b*CIN + ob)*NTOT + n;
          op[0*NTOT] = v0; op[1*NTOT] = v1; op[2*NTOT] = v2; op[3*NTOT] = v3;
        }
      }
    }
  }
}

// ---------------------------------------------------------------------------
// fp16 MFMA attention (R10 body verbatim + XCD swizzle): exp2 domain, no
// max-tracking, shuffle-free P->PV, 16 waves = one (b,h) x 512 queries,
// 96 KB LDS, one-step-ahead QK rotation (proven no-spill).  The swizzle
// co-locates the two half-blocks of each bh on one XCD so K/V is fetched
// from HBM once and served to the sibling from L2.
// ---------------------------------------------------------------------------
__global__ __launch_bounds__(1024) void attn_mfma(
    const u16* __restrict__ Qt,  // [bh][n][16] fp16 (x log2e folded)
    const u16* __restrict__ Kt,  // [bh][plane2][m][8] fp16
    const u16* __restrict__ Vt,  // [bh][mb16][g2][d32][8] fp16
    u16* __restrict__ Ot)        // [b][n][256c] fp16 (relu'd)
{
  __shared__ u16 K_lds[2*NTOT*8];   // 32 KB
  __shared__ u16 V_lds[4096*8];     // 64 KB
  const int t    = threadIdx.x;
  const int lane = t & 63;
  const int wave = t >> 6;
  const int bid  = blockIdx.x;
  const int wgid = (bid & 7)*32 + (bid >> 3);   // XCD swizzle (256 = 8*32)
  const int bh   = wgid >> 1;
  const int half = wgid & 1;
  const int g = lane >> 5, nl = lane & 31;
  const int n0 = half*512 + wave*32;

  const u16* Kh = Kt + (size_t)bh*(2*NTOT*8);
  const u16* Vh = Vt + (size_t)bh*(4096*8);
  const u16* Qh = Qt + (size_t)bh*(NTOT*KD);

  #pragma unroll
  for (int r = 0; r < 2; ++r) {
    const int uu = r*1024 + t;
    *(uint4*)&K_lds[uu*8] = *(const uint4*)&Kh[uu*8];
  }
  #pragma unroll
  for (int r = 0; r < 4; ++r) {
    const int uu = r*1024 + t;
    *(uint4*)&V_lds[uu*8] = *(const uint4*)&Vh[uu*8];
  }

  const f16x8 qf = as_f16x8(*(const uint4*)&Qh[(size_t)(n0+nl)*KD + g*8]);
  __syncthreads();

  const f32x16 fzero = {};
  f32x16 acc = {};
  float l0 = 0.f, l1 = 0.f, l2 = 0.f, l3 = 0.f;
  const char* Kb = (const char*)K_lds + g*16384 + nl*16;  // + step*512
  const char* Vb = (const char*)V_lds + g*512   + nl*16;  // + step*2048 (+1024)

  f16x8 kf  = as_f16x8(*(const uint4*)(Kb));
  uint4 va0 = *(const uint4*)(Vb);
  uint4 va1 = *(const uint4*)(Vb + 1024);
  f32x16 s_cur = __builtin_amdgcn_mfma_f32_32x32x16_f16(kf, qf, fzero, 0, 0, 0);

  #pragma unroll 2
  for (int st = 0; st < 31; ++st) {
    // next step's K frag + QK MFMA, issued before processing current scores
    const f16x8 kfn = as_f16x8(*(const uint4*)(Kb + (st+1)*512));
    __builtin_amdgcn_s_setprio(1);
    const f32x16 s_next = __builtin_amdgcn_mfma_f32_32x32x16_f16(kfn, qf, fzero, 0, 0, 0);
    __builtin_amdgcn_s_setprio(0);
    const uint4 nva0 = *(const uint4*)(Vb + (st+1)*2048);
    const uint4 nva1 = *(const uint4*)(Vb + (st+1)*2048 + 1024);

    // ---- half 0: m-slots 0..7 ----
    {
      float p[8];
      #pragma unroll
      for (int r = 0; r < 8; ++r) p[r] = fexp2(s_cur[r]);
      uint4 pb0;
      pb0.x = pkrtz(p[0], p[1]); pb0.y = pkrtz(p[2], p[3]);
      pb0.z = pkrtz(p[4], p[5]); pb0.w = pkrtz(p[6], p[7]);
      l0 = dot2acc(pb0.x, l0); l1 = dot2acc(pb0.y, l1);
      l2 = dot2acc(pb0.z, l2); l3 = dot2acc(pb0.w, l3);
      __builtin_amdgcn_s_setprio(1);
      acc = __builtin_amdgcn_mfma_f32_32x32x16_f16(as_f16x8(va0), as_f16x8(pb0), acc, 0, 0, 0);
      __builtin_amdgcn_s_setprio(0);
    }
    // ---- half 1: m-slots 8..15 ----
    {
      float p[8];
      #pragma unroll
      for (int r = 0; r < 8; ++r) p[r] = fexp2(s_cur[8+r]);
      uint4 pb1;
      pb1.x = pkrtz(p[0], p[1]); pb1.y = pkrtz(p[2], p[3]);
      pb1.z = pkrtz(p[4], p[5]); pb1.w = pkrtz(p[6], p[7]);
      l0 = dot2acc(pb1.x, l0); l1 = dot2acc(pb1.y, l1);
      l2 = dot2acc(pb1.z, l2); l3 = dot2acc(pb1.w, l3);
      __builtin_amdgcn_s_setprio(1);
      acc = __builtin_amdgcn_mfma_f32_32x32x16_f16(as_f16x8(va1), as_f16x8(pb1), acc, 0, 0, 0);
      __builtin_amdgcn_s_setprio(0);
    }
    s_cur = s_next; va0 = nva0; va1 = nva1;
  }
  { // last step (st = 31), no prefetch
    {
      float p[8];
      #pragma unroll
      for (int r = 0; r < 8; ++r) p[r] = fexp2(s_cur[r]);
      uint4 pb0;
      pb0.x = pkrtz(p[0], p[1]); pb0.y = pkrtz(p[2], p[3]);
      pb0.z = pkrtz(p[4], p[5]); pb0.w = pkrtz(p[6], p[7]);
      l0 = dot2acc(pb0.x, l0); l1 = dot2acc(pb0.y, l1);
      l2 = dot2acc(pb0.z, l2); l3 = dot2acc(pb0.w, l3);
      acc = __builtin_amdgcn_mfma_f32_32x32x16_f16(as_f16x8(va0), as_f16x8(pb0), acc, 0, 0, 0);
    }
    {
      float p[8];
      #pragma unroll
      for (int r = 0; r < 8; ++r) p[r] = fexp2(s_cur[8+r]);
      uint4 pb1;
      pb1.x = pkrtz(p[0], p[1]); pb1.y = pkrtz(p[2], p[3]);
      pb1.z = pkrtz(p[4], p[5]); pb1.w = pkrtz(p[6], p[7]);
      l0 = dot2acc(pb1.x, l0); l1 = dot2acc(pb1.y, l1);
      l2 = dot2acc(pb1.z, l2); l3 = dot2acc(pb1.w, l3);
      acc = __builtin_amdgcn_mfma_f32_32x32x16_f16(as_f16x8(va1), as_f16x8(pb1), acc, 0, 0, 0);
    }
  }

  const float lp = (l0 + l1) + (l2 + l3);
  const float lt = lp + __shfl_xor(lp, 32);
  const float rl = 1.0f / lt;
  const int b = bh >> 3, h = bh & 7;
  u16* op = Ot + ((size_t)b*NTOT + n0 + nl)*CIN + h*DV;
  #pragma unroll
  for (int q = 0; q < 4; ++q) {
    const float v0 = fmaxf(acc[4*q+0]*rl, 0.f);
    const float v1 = fmaxf(acc[4*q+1]*rl, 0.f);
    const float v2 = fmaxf(acc[4*q+2]*rl, 0.f);
    const float v3 = fmaxf(acc[4*q+3]*rl, 0.f);
    uint2 pk; pk.x = pkrtz(v0, v1); pk.y = pkrtz(v2, v3);
    *(uint2*)&op[8*q + 4*g] = pk;   // c = h*32 + 8q + 4g + {0..3}
  }
}

// ---------------------------------------------------------------------------
extern "C" void kernel_launch(void* const* d_in, const int* in_sizes, int n_in,
                              void* d_out, int out_size, void* d_ws, size_t ws_size,
                              hipStream_t stream) {
  const float* x  = (const float*)d_in[0];
  const float* wq = (const float*)d_in[1];
  const float* sq = (const float*)d_in[2];
  const float* bq = (const float*)d_in[3];
  const float* wk = (const float*)d_in[4];
  const float* sk = (const float*)d_in[5];
  const float* bk = (const float*)d_in[6];
  const float* wv = (const float*)d_in[7];
  const float* sv = (const float*)d_in[8];
  const float* bv = (const float*)d_in[9];
  const float* wp = (const float*)d_in[10];
  const float* sp = (const float*)d_in[11];
  const float* bp = (const float*)d_in[12];
  float* out = (float*)d_out;

  // ws: x_t/o_t overlay @0 (8MB) | q_t @8M | k_t @12M | v_h @16M (8MB) |
  //     wqkv @24M | wph | ball
  char* ws = (char*)d_ws;
  u16*   x_t  = (u16*)(ws);
  u16*   q_t  = (u16*)(ws + (8u  << 20));
  u16*   k_t  = (u16*)(ws + (12u << 20));
  u16*   v_h  = (u16*)(ws + (16u << 20));
  u16*   wqkv = (u16*)(ws + (24u << 20));
  u16*   wph  = (u16*)(ws + (24u << 20) + (256u << 10));
  float* ball = (float*)(ws + (24u << 20) + (384u << 10));

  prep_fused<<<dim3(1216), dim3(256), 0, stream>>>(
      x, x_t, wq, sq, bq, wk, sk, bk, wv, sv, bv, wp, sp, bp, wqkv, wph, ball);
  conv_mfma<128, 0><<<dim3(8, 4, 16), dim3(256), 0, stream>>>(
      wqkv, x_t, ball, q_t, k_t, v_h, nullptr);
  attn_mfma<<<dim3(256), dim3(1024), 0, stream>>>(q_t, k_t, v_h, x_t /* o_t */);
  conv_mfma<64, 1><<<dim3(16, 2, 16), dim3(256), 0, stream>>>(
      wph, x_t /* o_t */, ball + 512, nullptr, nullptr, nullptr, out);
}